// Round 1
// baseline (716.272 us; speedup 1.0000x reference)
//
#include <hip/hip_runtime.h>

#define N_NODES 100000
#define N_EDGES 300000
#define R_REL   2
#define DIM     128

// ---------------------------------------------------------------------------
// Pass 1: per-node attention scores. One wave per node.
// sS[r*N+n] = x[n] . attn_w[r][0:128],  sD[r*N+n] = x[n] . attn_w[r][128:256]
// ---------------------------------------------------------------------------
__global__ __launch_bounds__(256) void node_scores_kernel(
    const float* __restrict__ x, const float* __restrict__ attn_w,
    float* __restrict__ sS, float* __restrict__ sD) {
  int wave  = (blockIdx.x * blockDim.x + threadIdx.x) >> 6;
  int lane  = threadIdx.x & 63;
  int nwave = (gridDim.x * blockDim.x) >> 6;
  // each lane owns 2 consecutive elements of each weight half
  float2 a0s = ((const float2*)(attn_w +   0))[lane];
  float2 a0d = ((const float2*)(attn_w + 128))[lane];
  float2 a1s = ((const float2*)(attn_w + 256))[lane];
  float2 a1d = ((const float2*)(attn_w + 384))[lane];
  for (int n = wave; n < N_NODES; n += nwave) {
    float2 v = ((const float2*)(x + (size_t)n * DIM))[lane];
    float p0s = v.x * a0s.x + v.y * a0s.y;
    float p0d = v.x * a0d.x + v.y * a0d.y;
    float p1s = v.x * a1s.x + v.y * a1s.y;
    float p1d = v.x * a1d.x + v.y * a1d.y;
    #pragma unroll
    for (int off = 32; off > 0; off >>= 1) {
      p0s += __shfl_down(p0s, off, 64);
      p0d += __shfl_down(p0d, off, 64);
      p1s += __shfl_down(p1s, off, 64);
      p1d += __shfl_down(p1d, off, 64);
    }
    if (lane == 0) {
      sS[n] = p0s;            sD[n] = p0d;
      sS[N_NODES + n] = p1s;  sD[N_NODES + n] = p1d;
    }
  }
}

// ---------------------------------------------------------------------------
// Pass 2: out = x @ W + bias   (also serves as the initializer of d_out)
// Block: 256 threads, W (128x128 fp32, 64KB) in LDS, 32-row x tile (16KB),
// each thread computes a 4-row x 4-col register tile.
// ---------------------------------------------------------------------------
__global__ __launch_bounds__(256) void gemm_kernel(
    const float* __restrict__ x, const float* __restrict__ W,
    const float* __restrict__ bias, float* __restrict__ out) {
  __shared__ float Wl[DIM * DIM];   // 64 KB
  __shared__ float Xl[32 * DIM];    // 16 KB
  int tid = threadIdx.x;
  for (int i = tid; i < DIM * DIM / 4; i += 256)
    ((float4*)Wl)[i] = ((const float4*)W)[i];
  int cg = tid & 31;   // col group: cols 4*cg .. 4*cg+3
  int rg = tid >> 5;   // row group: rows rg*4 .. rg*4+3 within tile
  float4 b = ((const float4*)bias)[cg];
  __syncthreads();

  for (int tile = blockIdx.x; tile < N_NODES / 32; tile += gridDim.x) {
    int row0 = tile * 32;
    __syncthreads();  // previous tile's Xl readers are done
    for (int i = tid; i < 32 * DIM / 4; i += 256)
      ((float4*)Xl)[i] = ((const float4*)(x + (size_t)row0 * DIM))[i];
    __syncthreads();

    float4 acc0 = b, acc1 = b, acc2 = b, acc3 = b;
    const float4* xr0 = (const float4*)(Xl + (rg * 4 + 0) * DIM);
    const float4* xr1 = (const float4*)(Xl + (rg * 4 + 1) * DIM);
    const float4* xr2 = (const float4*)(Xl + (rg * 4 + 2) * DIM);
    const float4* xr3 = (const float4*)(Xl + (rg * 4 + 3) * DIM);
    #pragma unroll 4
    for (int k4 = 0; k4 < DIM / 4; k4++) {
      float4 w0 = ((const float4*)(Wl + (4 * k4 + 0) * DIM))[cg];
      float4 w1 = ((const float4*)(Wl + (4 * k4 + 1) * DIM))[cg];
      float4 w2 = ((const float4*)(Wl + (4 * k4 + 2) * DIM))[cg];
      float4 w3 = ((const float4*)(Wl + (4 * k4 + 3) * DIM))[cg];
      float4 x0 = xr0[k4], x1 = xr1[k4], x2 = xr2[k4], x3 = xr3[k4];
      acc0.x += x0.x*w0.x + x0.y*w1.x + x0.z*w2.x + x0.w*w3.x;
      acc0.y += x0.x*w0.y + x0.y*w1.y + x0.z*w2.y + x0.w*w3.y;
      acc0.z += x0.x*w0.z + x0.y*w1.z + x0.z*w2.z + x0.w*w3.z;
      acc0.w += x0.x*w0.w + x0.y*w1.w + x0.z*w2.w + x0.w*w3.w;
      acc1.x += x1.x*w0.x + x1.y*w1.x + x1.z*w2.x + x1.w*w3.x;
      acc1.y += x1.x*w0.y + x1.y*w1.y + x1.z*w2.y + x1.w*w3.y;
      acc1.z += x1.x*w0.z + x1.y*w1.z + x1.z*w2.z + x1.w*w3.z;
      acc1.w += x1.x*w0.w + x1.y*w1.w + x1.z*w2.w + x1.w*w3.w;
      acc2.x += x2.x*w0.x + x2.y*w1.x + x2.z*w2.x + x2.w*w3.x;
      acc2.y += x2.x*w0.y + x2.y*w1.y + x2.z*w2.y + x2.w*w3.y;
      acc2.z += x2.x*w0.z + x2.y*w1.z + x2.z*w2.z + x2.w*w3.z;
      acc2.w += x2.x*w0.w + x2.y*w1.w + x2.z*w2.w + x2.w*w3.w;
      acc3.x += x3.x*w0.x + x3.y*w1.x + x3.z*w2.x + x3.w*w3.x;
      acc3.y += x3.x*w0.y + x3.y*w1.y + x3.z*w2.y + x3.w*w3.y;
      acc3.z += x3.x*w0.z + x3.y*w1.z + x3.z*w2.z + x3.w*w3.z;
      acc3.w += x3.x*w0.w + x3.y*w1.w + x3.z*w2.w + x3.w*w3.w;
    }
    ((float4*)(out + (size_t)(row0 + rg * 4 + 0) * DIM))[cg] = acc0;
    ((float4*)(out + (size_t)(row0 + rg * 4 + 1) * DIM))[cg] = acc1;
    ((float4*)(out + (size_t)(row0 + rg * 4 + 2) * DIM))[cg] = acc2;
    ((float4*)(out + (size_t)(row0 + rg * 4 + 3) * DIM))[cg] = acc3;
  }
}

// ---------------------------------------------------------------------------
// Pass 3: per-edge p = exp(e) (no max-shift needed: |e| <~ 6) + denom sum.
// ---------------------------------------------------------------------------
__global__ __launch_bounds__(256) void edge_p_kernel(
    const int* __restrict__ src, const int* __restrict__ dst,
    const float* __restrict__ sS, const float* __restrict__ sD,
    float* __restrict__ p, float* __restrict__ denom) {
  int idx = blockIdx.x * blockDim.x + threadIdx.x;
  if (idx >= R_REL * N_EDGES) return;
  int r = idx / N_EDGES;
  int s = src[idx];
  int d = dst[idx];
  float e = sS[r * N_NODES + s] + sD[r * N_NODES + d];
  float pe = __expf(e);
  p[idx] = pe;
  atomicAdd(&denom[r * N_NODES + d], pe);
}

// ---------------------------------------------------------------------------
// Pass 4: one wave per (relation, edge): out[dst] += alpha * x[src]
// ---------------------------------------------------------------------------
__global__ __launch_bounds__(256) void scatter_kernel(
    const int* __restrict__ src, const int* __restrict__ dst,
    const float* __restrict__ p, const float* __restrict__ denom,
    const float* __restrict__ x, float* __restrict__ out) {
  int wave = (blockIdx.x * blockDim.x + threadIdx.x) >> 6;
  int lane = threadIdx.x & 63;
  if (wave >= R_REL * N_EDGES) return;
  int r = wave / N_EDGES;
  int s = src[wave];
  int d = dst[wave];
  float alpha = p[wave] / denom[r * N_NODES + d];
  float2 v = ((const float2*)(x + (size_t)s * DIM))[lane];
  float* o = out + (size_t)d * DIM + 2 * lane;
  atomicAdd(o,     alpha * v.x);
  atomicAdd(o + 1, alpha * v.y);
}

extern "C" void kernel_launch(void* const* d_in, const int* in_sizes, int n_in,
                              void* d_out, int out_size, void* d_ws, size_t ws_size,
                              hipStream_t stream) {
  const float* x      = (const float*)d_in[0];
  const float* attn_w = (const float*)d_in[1];
  const float* loop_w = (const float*)d_in[2];
  const float* h_bias = (const float*)d_in[3];
  const int*   src    = (const int*)d_in[4];
  const int*   dst    = (const int*)d_in[5];
  float*       out    = (float*)d_out;

  // workspace layout (fp32): sS[R*N] | sD[R*N] | denom[R*N] | p[R*E]
  float* sS    = (float*)d_ws;
  float* sD    = sS + R_REL * N_NODES;
  float* denom = sD + R_REL * N_NODES;
  float* p     = denom + R_REL * N_NODES;

  hipMemsetAsync(denom, 0, R_REL * N_NODES * sizeof(float), stream);

  node_scores_kernel<<<N_NODES / 4, 256, 0, stream>>>(x, attn_w, sS, sD);
  gemm_kernel<<<N_NODES / 32, 256, 0, stream>>>(x, loop_w, h_bias, out);
  edge_p_kernel<<<(R_REL * N_EDGES + 255) / 256, 256, 0, stream>>>(src, dst, sS, sD, p, denom);
  scatter_kernel<<<R_REL * N_EDGES / 4, 256, 0, stream>>>(src, dst, p, denom, x, out);
}

// Round 2
// 338.548 us; speedup vs baseline: 2.1157x; 2.1157x over previous
//
#include <hip/hip_runtime.h>

#define N_NODES 100000
#define N_EDGES 300000
#define R_REL   2
#define DIM     128
#define NBINS   (R_REL * N_NODES)          // 200000
#define SCAN_CHUNK 1024
#define SCAN_NB    ((NBINS + SCAN_CHUNK - 1) / SCAN_CHUNK)  // 196

// ---------------------------------------------------------------------------
// Pass 1: per-node attention scores. One wave per node.
// ---------------------------------------------------------------------------
__global__ __launch_bounds__(256) void node_scores_kernel(
    const float* __restrict__ x, const float* __restrict__ attn_w,
    float* __restrict__ sS, float* __restrict__ sD) {
  int wave  = (blockIdx.x * blockDim.x + threadIdx.x) >> 6;
  int lane  = threadIdx.x & 63;
  int nwave = (gridDim.x * blockDim.x) >> 6;
  float2 a0s = ((const float2*)(attn_w +   0))[lane];
  float2 a0d = ((const float2*)(attn_w + 128))[lane];
  float2 a1s = ((const float2*)(attn_w + 256))[lane];
  float2 a1d = ((const float2*)(attn_w + 384))[lane];
  for (int n = wave; n < N_NODES; n += nwave) {
    float2 v = ((const float2*)(x + (size_t)n * DIM))[lane];
    float p0s = v.x * a0s.x + v.y * a0s.y;
    float p0d = v.x * a0d.x + v.y * a0d.y;
    float p1s = v.x * a1s.x + v.y * a1s.y;
    float p1d = v.x * a1d.x + v.y * a1d.y;
    #pragma unroll
    for (int off = 32; off > 0; off >>= 1) {
      p0s += __shfl_down(p0s, off, 64);
      p0d += __shfl_down(p0d, off, 64);
      p1s += __shfl_down(p1s, off, 64);
      p1d += __shfl_down(p1d, off, 64);
    }
    if (lane == 0) {
      sS[n] = p0s;            sD[n] = p0d;
      sS[N_NODES + n] = p1s;  sD[N_NODES + n] = p1d;
    }
  }
}

// ---------------------------------------------------------------------------
// Pass 2: out = x @ W + bias   (initializes d_out; aggregate adds on top)
// ---------------------------------------------------------------------------
__global__ __launch_bounds__(256) void gemm_kernel(
    const float* __restrict__ x, const float* __restrict__ W,
    const float* __restrict__ bias, float* __restrict__ out) {
  __shared__ float Wl[DIM * DIM];   // 64 KB
  __shared__ float Xl[32 * DIM];    // 16 KB
  int tid = threadIdx.x;
  for (int i = tid; i < DIM * DIM / 4; i += 256)
    ((float4*)Wl)[i] = ((const float4*)W)[i];
  int cg = tid & 31;
  int rg = tid >> 5;
  float4 b = ((const float4*)bias)[cg];
  __syncthreads();

  for (int tile = blockIdx.x; tile < N_NODES / 32; tile += gridDim.x) {
    int row0 = tile * 32;
    __syncthreads();
    for (int i = tid; i < 32 * DIM / 4; i += 256)
      ((float4*)Xl)[i] = ((const float4*)(x + (size_t)row0 * DIM))[i];
    __syncthreads();

    float4 acc0 = b, acc1 = b, acc2 = b, acc3 = b;
    const float4* xr0 = (const float4*)(Xl + (rg * 4 + 0) * DIM);
    const float4* xr1 = (const float4*)(Xl + (rg * 4 + 1) * DIM);
    const float4* xr2 = (const float4*)(Xl + (rg * 4 + 2) * DIM);
    const float4* xr3 = (const float4*)(Xl + (rg * 4 + 3) * DIM);
    #pragma unroll 4
    for (int k4 = 0; k4 < DIM / 4; k4++) {
      float4 w0 = ((const float4*)(Wl + (4 * k4 + 0) * DIM))[cg];
      float4 w1 = ((const float4*)(Wl + (4 * k4 + 1) * DIM))[cg];
      float4 w2 = ((const float4*)(Wl + (4 * k4 + 2) * DIM))[cg];
      float4 w3 = ((const float4*)(Wl + (4 * k4 + 3) * DIM))[cg];
      float4 x0 = xr0[k4], x1 = xr1[k4], x2 = xr2[k4], x3 = xr3[k4];
      acc0.x += x0.x*w0.x + x0.y*w1.x + x0.z*w2.x + x0.w*w3.x;
      acc0.y += x0.x*w0.y + x0.y*w1.y + x0.z*w2.y + x0.w*w3.y;
      acc0.z += x0.x*w0.z + x0.y*w1.z + x0.z*w2.z + x0.w*w3.z;
      acc0.w += x0.x*w0.w + x0.y*w1.w + x0.z*w2.w + x0.w*w3.w;
      acc1.x += x1.x*w0.x + x1.y*w1.x + x1.z*w2.x + x1.w*w3.x;
      acc1.y += x1.x*w0.y + x1.y*w1.y + x1.z*w2.y + x1.w*w3.y;
      acc1.z += x1.x*w0.z + x1.y*w1.z + x1.z*w2.z + x1.w*w3.z;
      acc1.w += x1.x*w0.w + x1.y*w1.w + x1.z*w2.w + x1.w*w3.w;
      acc2.x += x2.x*w0.x + x2.y*w1.x + x2.z*w2.x + x2.w*w3.x;
      acc2.y += x2.x*w0.y + x2.y*w1.y + x2.z*w2.y + x2.w*w3.y;
      acc2.z += x2.x*w0.z + x2.y*w1.z + x2.z*w2.z + x2.w*w3.z;
      acc2.w += x2.x*w0.w + x2.y*w1.w + x2.z*w2.w + x2.w*w3.w;
      acc3.x += x3.x*w0.x + x3.y*w1.x + x3.z*w2.x + x3.w*w3.x;
      acc3.y += x3.x*w0.y + x3.y*w1.y + x3.z*w2.y + x3.w*w3.y;
      acc3.z += x3.x*w0.z + x3.y*w1.z + x3.z*w2.z + x3.w*w3.z;
      acc3.w += x3.x*w0.w + x3.y*w1.w + x3.z*w2.w + x3.w*w3.w;
    }
    ((float4*)(out + (size_t)(row0 + rg * 4 + 0) * DIM))[cg] = acc0;
    ((float4*)(out + (size_t)(row0 + rg * 4 + 1) * DIM))[cg] = acc1;
    ((float4*)(out + (size_t)(row0 + rg * 4 + 2) * DIM))[cg] = acc2;
    ((float4*)(out + (size_t)(row0 + rg * 4 + 3) * DIM))[cg] = acc3;
  }
}

// ---------------------------------------------------------------------------
// Counting sort of edges by (relation, dst): hist -> scan -> bin
// ---------------------------------------------------------------------------
__global__ __launch_bounds__(256) void hist_kernel(
    const int* __restrict__ dst, int* __restrict__ counts) {
  int idx = blockIdx.x * blockDim.x + threadIdx.x;
  if (idx >= R_REL * N_EDGES) return;
  int bin = (idx < N_EDGES ? 0 : N_NODES) + dst[idx];
  atomicAdd(&counts[bin], 1);
}

__global__ __launch_bounds__(256) void scan_phase1_kernel(
    const int* __restrict__ counts, int* __restrict__ bsum) {
  __shared__ int red[256];
  int b = blockIdx.x, t = threadIdx.x;
  int base = b * SCAN_CHUNK + t * 4;
  int s = 0;
  #pragma unroll
  for (int i = 0; i < 4; i++) {
    int k = base + i;
    if (k < NBINS) s += counts[k];
  }
  red[t] = s; __syncthreads();
  for (int off = 128; off > 0; off >>= 1) {
    if (t < off) red[t] += red[t + off];
    __syncthreads();
  }
  if (t == 0) bsum[b] = red[0];
}

__global__ __launch_bounds__(256) void scan_phase2_kernel(int* __restrict__ bsum) {
  __shared__ int tmp[256];
  int t = threadIdx.x;
  int v = (t < SCAN_NB) ? bsum[t] : 0;
  tmp[t] = v; __syncthreads();
  for (int off = 1; off < 256; off <<= 1) {
    int add = (t >= off) ? tmp[t - off] : 0;
    __syncthreads();
    tmp[t] += add;
    __syncthreads();
  }
  if (t < SCAN_NB) bsum[t] = (t == 0) ? 0 : tmp[t - 1];  // exclusive
}

__global__ __launch_bounds__(256) void scan_phase3_kernel(
    const int* __restrict__ counts, const int* __restrict__ bsum,
    int* __restrict__ offs) {
  __shared__ int tmp[256];
  int b = blockIdx.x, t = threadIdx.x;
  int base = b * SCAN_CHUNK + t * 4;
  int e[4]; int tsum = 0;
  #pragma unroll
  for (int i = 0; i < 4; i++) {
    int k = base + i;
    e[i] = (k < NBINS) ? counts[k] : 0;
    tsum += e[i];
  }
  tmp[t] = tsum; __syncthreads();
  for (int off = 1; off < 256; off <<= 1) {
    int add = (t >= off) ? tmp[t - off] : 0;
    __syncthreads();
    tmp[t] += add;
    __syncthreads();
  }
  int run = bsum[b] + tmp[t] - tsum;  // exclusive prefix for this thread
  #pragma unroll
  for (int i = 0; i < 4; i++) {
    int k = base + i;
    if (k < NBINS) offs[k] = run;
    run += e[i];
  }
}

// bin: pos = offs[bin]++ (atomic); sorted_src[pos] = src. After this pass,
// offs[bin] == end offset of the bin (beg = end - counts[bin]).
__global__ __launch_bounds__(256) void bin_kernel(
    const int* __restrict__ src, const int* __restrict__ dst,
    int* __restrict__ offs, int* __restrict__ sorted_src) {
  int idx = blockIdx.x * blockDim.x + threadIdx.x;
  if (idx >= R_REL * N_EDGES) return;
  int bin = (idx < N_EDGES ? 0 : N_NODES) + dst[idx];
  int pos = atomicAdd(&offs[bin], 1);
  sorted_src[pos] = src[idx];
}

// ---------------------------------------------------------------------------
// Aggregate: one wave per destination node, both relations, zero fp32 atomics.
// ---------------------------------------------------------------------------
__global__ __launch_bounds__(256) void aggregate_kernel(
    const int* __restrict__ sorted_src, const int* __restrict__ offs,
    const int* __restrict__ counts, const float* __restrict__ sS,
    const float* __restrict__ sD, const float* __restrict__ x,
    float* __restrict__ out) {
  int wave = (blockIdx.x * blockDim.x + threadIdx.x) >> 6;
  int lane = threadIdx.x & 63;
  if (wave >= N_NODES) return;
  int n = wave;
  float2 acc = make_float2(0.f, 0.f);
  #pragma unroll
  for (int r = 0; r < R_REL; r++) {
    int bin = r * N_NODES + n;
    int cnt = counts[bin];
    if (cnt == 0) continue;
    int end = offs[bin];       // end offset (post bin_kernel)
    int beg = end - cnt;
    float sDn = sD[bin];
    float denom = 0.f;
    float2 accr = make_float2(0.f, 0.f);
    for (int c = beg; c < end; c += 64) {
      int m = min(64, end - c);
      int   sj = 0;
      float pj = 0.f;
      if (lane < m) {
        sj = sorted_src[c + lane];
        pj = __expf(sS[r * N_NODES + sj] + sDn);
      }
      float ps = pj;
      #pragma unroll
      for (int off = 32; off > 0; off >>= 1) ps += __shfl_xor(ps, off, 64);
      denom += ps;
      for (int j = 0; j < m; j++) {
        int   s = __shfl(sj, j, 64);
        float p = __shfl(pj, j, 64);
        float2 v = ((const float2*)(x + (size_t)s * DIM))[lane];
        accr.x += p * v.x;
        accr.y += p * v.y;
      }
    }
    float inv = 1.f / denom;
    acc.x += accr.x * inv;
    acc.y += accr.y * inv;
  }
  float2* o = (float2*)(out + (size_t)n * DIM) + lane;
  float2 cur = *o;
  cur.x += acc.x; cur.y += acc.y;
  *o = cur;
}

extern "C" void kernel_launch(void* const* d_in, const int* in_sizes, int n_in,
                              void* d_out, int out_size, void* d_ws, size_t ws_size,
                              hipStream_t stream) {
  const float* x      = (const float*)d_in[0];
  const float* attn_w = (const float*)d_in[1];
  const float* loop_w = (const float*)d_in[2];
  const float* h_bias = (const float*)d_in[3];
  const int*   src    = (const int*)d_in[4];
  const int*   dst    = (const int*)d_in[5];
  float*       out    = (float*)d_out;

  // workspace: sS[2N] f32 | sD[2N] f32 | counts[2N] i32 | offs[2N] i32 |
  //            sorted_src[2E] i32 | bsum[256] i32       (~5.6 MB)
  float* sS     = (float*)d_ws;
  float* sD     = sS + NBINS;
  int*   counts = (int*)(sD + NBINS);
  int*   offs   = counts + NBINS;
  int*   sorted = offs + NBINS;
  int*   bsum   = sorted + R_REL * N_EDGES;

  hipMemsetAsync(counts, 0, NBINS * sizeof(int), stream);

  node_scores_kernel<<<N_NODES / 4, 256, 0, stream>>>(x, attn_w, sS, sD);
  gemm_kernel<<<N_NODES / 32, 256, 0, stream>>>(x, loop_w, h_bias, out);
  hist_kernel<<<(R_REL * N_EDGES + 255) / 256, 256, 0, stream>>>(dst, counts);
  scan_phase1_kernel<<<SCAN_NB, 256, 0, stream>>>(counts, bsum);
  scan_phase2_kernel<<<1, 256, 0, stream>>>(bsum);
  scan_phase3_kernel<<<SCAN_NB, 256, 0, stream>>>(counts, bsum, offs);
  bin_kernel<<<(R_REL * N_EDGES + 255) / 256, 256, 0, stream>>>(src, dst, offs, sorted);
  aggregate_kernel<<<(N_NODES + 3) / 4, 256, 0, stream>>>(sorted, offs, counts, sS, sD, x, out);
}